// Round 1
// baseline (695.068 us; speedup 1.0000x reference)
//
#include <hip/hip_runtime.h>

typedef unsigned short u16;
typedef __attribute__((ext_vector_type(8))) short short8;
typedef __attribute__((ext_vector_type(8))) unsigned short ushort8;
typedef __attribute__((ext_vector_type(4))) float f32x4;

static constexpr int Cdim = 768;
static constexpr int Hdim = 3072;
static constexpr int Edim = 8;
static constexpr int Ntok = 4096;   // B*T
static constexpr int DR  = 24;

// ---- workspace layout (bytes) ----
static constexpr size_t OFF_XB   = 0;                          // x bf16: N*C*2 = 6,291,456
static constexpr size_t OFF_W1C  = 6291456;                    // 8*768*3072*2 = 37,748,736
static constexpr size_t OFF_W2C  = 44040192;                   // 37,748,736
static constexpr size_t OFF_HBUF = 81788928;                   // 8192*3072*2 = 50,331,648
static constexpr size_t OFF_TOK  = 132120576;                  // E*N*4
static constexpr size_t OFF_GATE = 132251648;                  // E*N*4
static constexpr size_t OFF_CNT  = 132382720;                  // 8*4
static constexpr size_t OFF_OFFS = 132382752;                  // 8*4

__device__ __forceinline__ u16 f2bf(float f) {
  unsigned u = __builtin_bit_cast(unsigned, f);
  u += 0x7fffu + ((u >> 16) & 1u);          // round-to-nearest-even
  return (u16)(u >> 16);
}

__device__ __forceinline__ float wred(float v) {
  #pragma unroll
  for (int m = 32; m > 0; m >>= 1) v += __shfl_xor(v, m, 64);
  return v;
}

// ---------- prep: x -> bf16 ----------
__global__ __launch_bounds__(256) void prep_x_kernel(const float* __restrict__ x,
                                                     u16* __restrict__ x16) {
  long i = ((long)blockIdx.x * 256 + threadIdx.x) * 8;
  const float4* A = reinterpret_cast<const float4*>(x + i);
  ushort8 o;
  #pragma unroll
  for (int q = 0; q < 2; q++) {
    float4 a = A[q];
    o[4*q+0] = f2bf(a.x); o[4*q+1] = f2bf(a.y);
    o[4*q+2] = f2bf(a.z); o[4*q+3] = f2bf(a.w);
  }
  *reinterpret_cast<ushort8*>(x16 + i) = o;
}

// ---------- prep: W = wf + mg*ws + hf -> bf16 ----------
__global__ __launch_bounds__(256) void prep_w_kernel(const float* __restrict__ wf,
                                                     const float* __restrict__ wsl,
                                                     const float* __restrict__ hf,
                                                     const float* __restrict__ mg,
                                                     u16* __restrict__ outw, const long CH) {
  long i = ((long)blockIdx.x * 256 + threadIdx.x) * 8;
  int e = (int)(i / CH);
  float m = mg[e];
  const float4* A = reinterpret_cast<const float4*>(wf + i);
  const float4* B = reinterpret_cast<const float4*>(wsl + i);
  const float4* Hh = reinterpret_cast<const float4*>(hf + i);
  ushort8 o;
  #pragma unroll
  for (int q = 0; q < 2; q++) {
    float4 a = A[q], b = B[q], h = Hh[q];
    o[4*q+0] = f2bf(fmaf(m, b.x, a.x) + h.x);
    o[4*q+1] = f2bf(fmaf(m, b.y, a.y) + h.y);
    o[4*q+2] = f2bf(fmaf(m, b.z, a.z) + h.z);
    o[4*q+3] = f2bf(fmaf(m, b.w, a.w) + h.w);
  }
  *reinterpret_cast<ushort8*>(outw + i) = o;
}

// ---------- router: logits, top-2, softmax, per-expert append ----------
__global__ __launch_bounds__(256)
void router_kernel(const float* __restrict__ x, const float* __restrict__ router_w,
                   const float* __restrict__ probe_w, const float* __restrict__ emb,
                   const float* __restrict__ fatigue, const float* __restrict__ energy,
                   int* __restrict__ counts, int* __restrict__ tok_list,
                   float* __restrict__ gate_list) {
  const int tid = threadIdx.x;
  const int lane = tid & 63, wv = tid >> 6;
  const int t = blockIdx.x * 4 + wv;
  const float* xr = x + (size_t)t * Cdim;

  float racc[Edim] = {};
  float pacc[DR] = {};
  float sacc = 0.f;
  for (int i = 0; i < Cdim / 64; i++) {
    int c = i * 64 + lane;
    float xv = xr[c];
    sacc += xv;
    #pragma unroll
    for (int ee = 0; ee < Edim; ee++) racc[ee] = fmaf(xv, router_w[ee * Cdim + c], racc[ee]);
    #pragma unroll
    for (int d = 0; d < DR; d++) pacc[d] = fmaf(xv, probe_w[d * Cdim + c], pacc[d]);
  }
  sacc = wred(sacc);
  #pragma unroll
  for (int ee = 0; ee < Edim; ee++) racc[ee] = wred(racc[ee]);
  #pragma unroll
  for (int d = 0; d < DR; d++) pacc[d] = wred(pacc[d]);

  if (lane == 0) {
    float proxy = sacc / 768.f;
    float pn2 = 0.f;
    #pragma unroll
    for (int d = 0; d < DR; d++) pn2 += pacc[d] * pacc[d];
    float pnorm = sqrtf(pn2);
    float logitv[Edim];
    #pragma unroll
    for (int ee = 0; ee < Edim; ee++) {
      float g2 = 0.f, dote = 0.f;
      #pragma unroll
      for (int d = 0; d < DR; d++) {
        float ev = emb[ee * DR + d];
        g2 += ev * ev;
        dote += pacc[d] * ev;
      }
      float gain = sqrtf(g2);
      float align = dote / (fmaxf(pnorm, 1e-12f) * fmaxf(gain, 1e-12f));
      logitv[ee] = racc[ee] + 0.02f * proxy * (1.f + gain) + 0.02f * align
                 + 0.1f * energy[ee] - 0.1f * fatigue[ee];
    }
    // top-2, ties -> lowest index (strict >)
    int e0 = 0; float b0v = logitv[0];
    #pragma unroll
    for (int ee = 1; ee < Edim; ee++) if (logitv[ee] > b0v) { b0v = logitv[ee]; e0 = ee; }
    int e1 = -1; float b1v = -3.4e38f;
    #pragma unroll
    for (int ee = 0; ee < Edim; ee++) if (ee != e0 && logitv[ee] > b1v) { b1v = logitv[ee]; e1 = ee; }
    float texp = expf(b1v - b0v);
    float g0 = 1.f / (1.f + texp);
    float g1 = texp / (1.f + texp);
    int p0 = atomicAdd(&counts[e0], 1);
    tok_list[e0 * Ntok + p0] = t; gate_list[e0 * Ntok + p0] = g0;
    int p1 = atomicAdd(&counts[e1], 1);
    tok_list[e1 * Ntok + p1] = t; gate_list[e1 * Ntok + p1] = g1;
  }
}

__global__ void offsets_kernel(const int* __restrict__ counts, int* __restrict__ offs) {
  if (threadIdx.x == 0) {
    int r = 0;
    for (int e = 0; e < Edim; e++) { offs[e] = r; r += counts[e]; }
  }
}

// ---------- fc1: h = relu(x @ W1 + b1)^2 (gathered rows), store bf16 ----------
__global__ __launch_bounds__(256)
void fc1_kernel(const u16* __restrict__ x16, const u16* __restrict__ W1c,
                const float* __restrict__ b1, const int* __restrict__ counts,
                const int* __restrict__ offs, const int* __restrict__ tok_list,
                u16* __restrict__ h_buf) {
  const int e = blockIdx.z;
  const int n_e = counts[e];
  const int tokBase = blockIdx.y * 64;
  if (tokBase >= n_e) return;
  const int hBase = blockIdx.x * 64;
  __shared__ u16 Asm[64][40];
  __shared__ u16 Bsm[64][40];
  __shared__ int toks[64];
  const int tid = threadIdx.x;
  if (tid < 64) {
    int s = tokBase + tid;
    toks[tid] = (s < n_e) ? tok_list[e * Ntok + s] : -1;
  }
  __syncthreads();
  const int lane = tid & 63, wv = tid >> 6;
  const int ar = tid >> 2, ak = (tid & 3) * 8;
  const int bk = tid >> 3, bh = (tid & 7) * 8;
  const int tokA = toks[ar];
  const u16* aSrc = (tokA >= 0) ? (x16 + (size_t)tokA * Cdim + ak) : nullptr;
  const u16* bSrc = W1c + ((size_t)e * Cdim + bk) * Hdim + hBase + bh;
  f32x4 acc[4] = {};
  const int fr = lane & 15, fk = (lane >> 4) * 8;
  for (int k0 = 0; k0 < Cdim; k0 += 32) {
    ushort8 av = {};
    if (aSrc) av = *reinterpret_cast<const ushort8*>(aSrc + k0);
    ushort8 bv = *reinterpret_cast<const ushort8*>(bSrc + (size_t)k0 * Hdim);
    __syncthreads();
    *reinterpret_cast<ushort8*>(&Asm[ar][ak]) = av;
    #pragma unroll
    for (int j = 0; j < 8; j++) Bsm[bh + j][bk] = bv[j];   // transpose into LDS
    __syncthreads();
    short8 bfrag = *reinterpret_cast<const short8*>(&Bsm[16 * wv + fr][fk]);
    #pragma unroll
    for (int m = 0; m < 4; m++) {
      short8 afrag = *reinterpret_cast<const short8*>(&Asm[16 * m + fr][fk]);
      acc[m] = __builtin_amdgcn_mfma_f32_16x16x32_bf16(afrag, bfrag, acc[m], 0, 0, 0);
    }
  }
  const int hcol = hBase + 16 * wv + fr;
  const float bias = b1[e * Hdim + hcol];
  const int rowB = offs[e] + tokBase;
  #pragma unroll
  for (int m = 0; m < 4; m++) {
    #pragma unroll
    for (int r = 0; r < 4; r++) {
      int tl = 16 * m + (lane >> 4) * 4 + r;
      if (tokBase + tl < n_e) {
        float v = acc[m][r] + bias;
        v = fmaxf(v, 0.f);
        h_buf[(size_t)(rowB + tl) * Hdim + hcol] = f2bf(v * v);
      }
    }
  }
}

// ---------- fc2: y = h @ W2 + b2; out[tok] += gate*y ----------
__global__ __launch_bounds__(256)
void fc2_kernel(const u16* __restrict__ h_buf, const u16* __restrict__ W2c,
                const float* __restrict__ b2, const int* __restrict__ counts,
                const int* __restrict__ offs, const int* __restrict__ tok_list,
                const float* __restrict__ gate_list, float* __restrict__ out) {
  const int e = blockIdx.z;
  const int n_e = counts[e];
  const int tokBase = blockIdx.y * 64;
  if (tokBase >= n_e) return;
  const int cBase = blockIdx.x * 64;
  __shared__ u16 Asm[64][40];
  __shared__ u16 Bsm[64][40];
  const int tid = threadIdx.x;
  const int lane = tid & 63, wv = tid >> 6;
  const int ar = tid >> 2, ak = (tid & 3) * 8;
  const int bk = tid >> 3, bc = (tid & 7) * 8;
  const int slotB = offs[e] + tokBase;
  const bool aValid = (tokBase + ar < n_e);
  const u16* aSrc = h_buf + (size_t)(slotB + ar) * Hdim + ak;
  const u16* bSrc = W2c + ((size_t)e * Hdim + bk) * Cdim + cBase + bc;
  f32x4 acc[4] = {};
  const int fr = lane & 15, fk = (lane >> 4) * 8;
  for (int k0 = 0; k0 < Hdim; k0 += 32) {
    ushort8 av = {};
    if (aValid) av = *reinterpret_cast<const ushort8*>(aSrc + k0);
    ushort8 bv = *reinterpret_cast<const ushort8*>(bSrc + (size_t)k0 * Cdim);
    __syncthreads();
    *reinterpret_cast<ushort8*>(&Asm[ar][ak]) = av;
    #pragma unroll
    for (int j = 0; j < 8; j++) Bsm[bc + j][bk] = bv[j];
    __syncthreads();
    short8 bfrag = *reinterpret_cast<const short8*>(&Bsm[16 * wv + fr][fk]);
    #pragma unroll
    for (int m = 0; m < 4; m++) {
      short8 afrag = *reinterpret_cast<const short8*>(&Asm[16 * m + fr][fk]);
      acc[m] = __builtin_amdgcn_mfma_f32_16x16x32_bf16(afrag, bfrag, acc[m], 0, 0, 0);
    }
  }
  const int ccol = cBase + 16 * wv + fr;
  const float bias = b2[e * Cdim + ccol];
  #pragma unroll
  for (int m = 0; m < 4; m++) {
    #pragma unroll
    for (int r = 0; r < 4; r++) {
      int tl = 16 * m + (lane >> 4) * 4 + r;
      int s = tokBase + tl;
      if (s < n_e) {
        int tok = tok_list[e * Ntok + s];
        float g = gate_list[e * Ntok + s];
        atomicAdd(&out[(size_t)tok * Cdim + ccol], g * (acc[m][r] + bias));
      }
    }
  }
}

extern "C" void kernel_launch(void* const* d_in, const int* in_sizes, int n_in,
                              void* d_out, int out_size, void* d_ws, size_t ws_size,
                              hipStream_t stream) {
  const float* x        = (const float*)d_in[0];
  const float* router_w = (const float*)d_in[1];
  const float* probe_w  = (const float*)d_in[2];
  const float* emb      = (const float*)d_in[3];
  const float* fatigue  = (const float*)d_in[4];
  const float* energy   = (const float*)d_in[5];
  const float* wf1      = (const float*)d_in[6];
  const float* ws1      = (const float*)d_in[7];
  const float* hf1      = (const float*)d_in[8];
  const float* mg1      = (const float*)d_in[9];
  const float* b1       = (const float*)d_in[10];
  const float* wf2      = (const float*)d_in[11];
  const float* ws2      = (const float*)d_in[12];
  const float* hf2      = (const float*)d_in[13];
  const float* mg2      = (const float*)d_in[14];
  const float* b2       = (const float*)d_in[15];
  float* out = (float*)d_out;
  char* ws = (char*)d_ws;

  u16*   x16       = (u16*)(ws + OFF_XB);
  u16*   W1c       = (u16*)(ws + OFF_W1C);
  u16*   W2c       = (u16*)(ws + OFF_W2C);
  u16*   hbuf      = (u16*)(ws + OFF_HBUF);
  int*   tok_list  = (int*)(ws + OFF_TOK);
  float* gate_list = (float*)(ws + OFF_GATE);
  int*   counts    = (int*)(ws + OFF_CNT);
  int*   offs      = (int*)(ws + OFF_OFFS);

  hipMemsetAsync(counts, 0, 64, stream);                              // counts + offs
  hipMemsetAsync(out, 0, (size_t)Ntok * Cdim * sizeof(float), stream);

  prep_x_kernel<<<1536, 256, 0, stream>>>(x, x16);
  prep_w_kernel<<<9216, 256, 0, stream>>>(wf1, ws1, hf1, mg1, W1c, (long)Cdim * Hdim);
  prep_w_kernel<<<9216, 256, 0, stream>>>(wf2, ws2, hf2, mg2, W2c, (long)Cdim * Hdim);
  router_kernel<<<1024, 256, 0, stream>>>(x, router_w, probe_w, emb, fatigue, energy,
                                          counts, tok_list, gate_list);
  offsets_kernel<<<1, 64, 0, stream>>>(counts, offs);
  fc1_kernel<<<dim3(Hdim / 64, 64, Edim), 256, 0, stream>>>(x16, W1c, b1, counts, offs,
                                                            tok_list, hbuf);
  fc2_kernel<<<dim3(Cdim / 64, 64, Edim), 256, 0, stream>>>(hbuf, W2c, b2, counts, offs,
                                                            tok_list, gate_list, out);
  (void)in_sizes; (void)n_in; (void)out_size; (void)ws_size;
}

// Round 2
// 410.803 us; speedup vs baseline: 1.6920x; 1.6920x over previous
//
#include <hip/hip_runtime.h>

typedef unsigned short u16;
typedef __attribute__((ext_vector_type(8))) short short8;
typedef __attribute__((ext_vector_type(8))) unsigned short ushort8;
typedef __attribute__((ext_vector_type(4))) float f32x4;

static constexpr int Cdim = 768;
static constexpr int Hdim = 3072;
static constexpr int Edim = 8;
static constexpr int Ntok = 4096;   // B*T
static constexpr int DRc  = 24;
static constexpr int NSLOT = Ntok * 2;  // 8192 (sum of counts)

// ---- workspace layout (bytes) ----
static constexpr size_t OFF_XB   = 0;                          // x bf16: N*C*2 = 6,291,456
static constexpr size_t OFF_W1T  = 6291456;                    // W1T [E][H][C] bf16: 37,748,736
static constexpr size_t OFF_W2T  = 44040192;                   // W2T [E][C][H] bf16: 37,748,736
static constexpr size_t OFF_HBUF = 81788928;                   // 8192*3072*2 = 50,331,648
static constexpr size_t OFF_TOK  = 132120576;                  // E*N*4
static constexpr size_t OFF_GATE = 132251648;                  // E*N*4
static constexpr size_t OFF_CNT  = 132382720;                  // 8*4
static constexpr size_t OFF_OFFS = 132382752;                  // 8*4

__device__ __forceinline__ u16 f2bf(float f) {
  unsigned u = __builtin_bit_cast(unsigned, f);
  u += 0x7fffu + ((u >> 16) & 1u);          // round-to-nearest-even
  return (u16)(u >> 16);
}

__device__ __forceinline__ float wred(float v) {
  #pragma unroll
  for (int m = 32; m > 0; m >>= 1) v += __shfl_xor(v, m, 64);
  return v;
}

// async global->LDS, 16B per lane (HW: wave-uniform LDS base + lane*16)
__device__ __forceinline__ void gld16(const u16* g, u16* l) {
  __builtin_amdgcn_global_load_lds((const __attribute__((address_space(1))) unsigned int*)g,
                                   (__attribute__((address_space(3))) unsigned int*)l,
                                   16, 0, 0);
}

// ---------- prep: x -> bf16 ----------
__global__ __launch_bounds__(256) void prep_x_kernel(const float* __restrict__ x,
                                                     u16* __restrict__ x16) {
  long i = ((long)blockIdx.x * 256 + threadIdx.x) * 8;
  const float4* A = reinterpret_cast<const float4*>(x + i);
  ushort8 o;
  #pragma unroll
  for (int q = 0; q < 2; q++) {
    float4 a = A[q];
    o[4*q+0] = f2bf(a.x); o[4*q+1] = f2bf(a.y);
    o[4*q+2] = f2bf(a.z); o[4*q+3] = f2bf(a.w);
  }
  *reinterpret_cast<ushort8*>(x16 + i) = o;
}

// ---------- prep: W = wf + mg*ws + hf -> bf16, TRANSPOSED ----------
// in: [E][R][Ccol] f32 x3   out: [E][Ccol][R] bf16
__global__ __launch_bounds__(256)
void prep_wt_kernel(const float* __restrict__ wf, const float* __restrict__ wsl,
                    const float* __restrict__ hf, const float* __restrict__ mg,
                    u16* __restrict__ outw, const int R, const int Ccol) {
  __shared__ u16 tileT[64][66];   // [col][row], pad 66 for bank spread
  const int e = blockIdx.z;
  const int r0 = blockIdx.x * 64, c0 = blockIdx.y * 64;
  const float m = mg[e];
  const size_t base = (size_t)e * R * Ccol;
  const int t = threadIdx.x;
  const int cr = t >> 4, cc = (t & 15) * 4;
  #pragma unroll
  for (int i = 0; i < 4; i++) {
    int r = cr + i * 16;
    size_t idx = base + (size_t)(r0 + r) * Ccol + (c0 + cc);
    float4 a = *(const float4*)(wf + idx);
    float4 b = *(const float4*)(wsl + idx);
    float4 h = *(const float4*)(hf + idx);
    tileT[cc + 0][r] = f2bf(fmaf(m, b.x, a.x) + h.x);
    tileT[cc + 1][r] = f2bf(fmaf(m, b.y, a.y) + h.y);
    tileT[cc + 2][r] = f2bf(fmaf(m, b.z, a.z) + h.z);
    tileT[cc + 3][r] = f2bf(fmaf(m, b.w, a.w) + h.w);
  }
  __syncthreads();
  const int oc = t >> 2, ch = (t & 3) * 16;
  ushort8 o0, o1;
  #pragma unroll
  for (int j = 0; j < 8; j++) { o0[j] = tileT[oc][ch + j]; o1[j] = tileT[oc][ch + 8 + j]; }
  size_t oidx = ((size_t)e * Ccol + c0 + oc) * R + r0 + ch;
  *reinterpret_cast<ushort8*>(outw + oidx) = o0;
  *reinterpret_cast<ushort8*>(outw + oidx + 8) = o1;
}

// ---------- router: logits, top-2, softmax, per-expert append ----------
__global__ __launch_bounds__(256)
void router_kernel(const float* __restrict__ x, const float* __restrict__ router_w,
                   const float* __restrict__ probe_w, const float* __restrict__ emb,
                   const float* __restrict__ fatigue, const float* __restrict__ energy,
                   int* __restrict__ counts, int* __restrict__ tok_list,
                   float* __restrict__ gate_list) {
  const int tid = threadIdx.x;
  const int lane = tid & 63, wv = tid >> 6;
  const int t = blockIdx.x * 4 + wv;
  const float* xr = x + (size_t)t * Cdim;

  float racc[Edim] = {};
  float pacc[DRc] = {};
  float sacc = 0.f;
  for (int i = 0; i < Cdim / 64; i++) {
    int c = i * 64 + lane;
    float xv = xr[c];
    sacc += xv;
    #pragma unroll
    for (int ee = 0; ee < Edim; ee++) racc[ee] = fmaf(xv, router_w[ee * Cdim + c], racc[ee]);
    #pragma unroll
    for (int d = 0; d < DRc; d++) pacc[d] = fmaf(xv, probe_w[d * Cdim + c], pacc[d]);
  }
  sacc = wred(sacc);
  #pragma unroll
  for (int ee = 0; ee < Edim; ee++) racc[ee] = wred(racc[ee]);
  #pragma unroll
  for (int d = 0; d < DRc; d++) pacc[d] = wred(pacc[d]);

  if (lane == 0) {
    float proxy = sacc / 768.f;
    float pn2 = 0.f;
    #pragma unroll
    for (int d = 0; d < DRc; d++) pn2 += pacc[d] * pacc[d];
    float pnorm = sqrtf(pn2);
    float logitv[Edim];
    #pragma unroll
    for (int ee = 0; ee < Edim; ee++) {
      float g2 = 0.f, dote = 0.f;
      #pragma unroll
      for (int d = 0; d < DRc; d++) {
        float ev = emb[ee * DRc + d];
        g2 += ev * ev;
        dote += pacc[d] * ev;
      }
      float gain = sqrtf(g2);
      float align = dote / (fmaxf(pnorm, 1e-12f) * fmaxf(gain, 1e-12f));
      logitv[ee] = racc[ee] + 0.02f * proxy * (1.f + gain) + 0.02f * align
                 + 0.1f * energy[ee] - 0.1f * fatigue[ee];
    }
    int e0 = 0; float b0v = logitv[0];
    #pragma unroll
    for (int ee = 1; ee < Edim; ee++) if (logitv[ee] > b0v) { b0v = logitv[ee]; e0 = ee; }
    int e1 = -1; float b1v = -3.4e38f;
    #pragma unroll
    for (int ee = 0; ee < Edim; ee++) if (ee != e0 && logitv[ee] > b1v) { b1v = logitv[ee]; e1 = ee; }
    float texp = expf(b1v - b0v);
    float g0 = 1.f / (1.f + texp);
    float g1 = texp / (1.f + texp);
    int p0 = atomicAdd(&counts[e0], 1);
    tok_list[e0 * Ntok + p0] = t; gate_list[e0 * Ntok + p0] = g0;
    int p1 = atomicAdd(&counts[e1], 1);
    tok_list[e1 * Ntok + p1] = t; gate_list[e1 * Ntok + p1] = g1;
  }
}

__global__ void offsets_kernel(const int* __restrict__ counts, int* __restrict__ offs) {
  if (threadIdx.x == 0) {
    int r = 0;
    for (int e = 0; e < Edim; e++) { offs[e] = r; r += counts[e]; }
  }
}

// ---------- fc1: h = relu(x @ W1 + b1)^2, 128x128 tile, BK=32 ----------
__global__ __launch_bounds__(256)
void fc1_kernel(const u16* __restrict__ x16, const u16* __restrict__ W1T,
                const float* __restrict__ b1, const int* __restrict__ counts,
                const int* __restrict__ offs, const int* __restrict__ tok_list,
                u16* __restrict__ h_buf) {
  const int e = blockIdx.z;
  const int n_e = counts[e];
  const int tokBase = blockIdx.y * 128;
  if (tokBase >= n_e) return;
  const int hBase = blockIdx.x * 128;
  __shared__ u16 As[128 * 32];
  __shared__ u16 Bs[128 * 32];
  __shared__ int toks[128];
  const int tid = threadIdx.x;
  if (tid < 128) {
    int s = tokBase + tid;
    toks[tid] = (s < n_e) ? tok_list[e * Ntok + s] : 0;
  }
  __syncthreads();
  const int lane = tid & 63, wv = tid >> 6;
  const int wr = wv >> 1, wc = wv & 1;
  const int sRow = lane >> 2, sSlot = lane & 3;
  const int kbOff = (sSlot ^ ((sRow >> 1) & 3)) * 8;     // swizzled source k-block
  const int rA0 = wv * 16 + sRow, rA1 = 64 + rA0;
  const u16* pA0 = x16 + (size_t)toks[rA0] * Cdim + kbOff;
  const u16* pA1 = x16 + (size_t)toks[rA1] * Cdim + kbOff;
  const u16* pB0 = W1T + ((size_t)e * Hdim + hBase + rA0) * Cdim + kbOff;
  const u16* pB1 = W1T + ((size_t)e * Hdim + hBase + rA1) * Cdim + kbOff;
  u16* ldsA0 = As + wv * 512 + lane * 8;
  u16* ldsA1 = As + 2048 + wv * 512 + lane * 8;
  u16* ldsB0 = Bs + wv * 512 + lane * 8;
  u16* ldsB1 = Bs + 2048 + wv * 512 + lane * 8;
  const int fr = lane & 15;
  const int qsw = (((lane >> 4) ^ ((fr >> 1) & 3))) * 8; // swizzled read slot
  f32x4 acc[4][4] = {};
  for (int k0 = 0; k0 < Cdim; k0 += 32) {
    gld16(pA0 + k0, ldsA0);
    gld16(pA1 + k0, ldsA1);
    gld16(pB0 + k0, ldsB0);
    gld16(pB1 + k0, ldsB1);
    __syncthreads();
    short8 aF[4], bF[4];
    #pragma unroll
    for (int m = 0; m < 4; m++)
      aF[m] = *reinterpret_cast<const short8*>(As + (wr * 64 + m * 16 + fr) * 32 + qsw);
    #pragma unroll
    for (int n = 0; n < 4; n++)
      bF[n] = *reinterpret_cast<const short8*>(Bs + (wc * 64 + n * 16 + fr) * 32 + qsw);
    #pragma unroll
    for (int m = 0; m < 4; m++)
      #pragma unroll
      for (int n = 0; n < 4; n++)
        acc[m][n] = __builtin_amdgcn_mfma_f32_16x16x32_bf16(aF[m], bF[n], acc[m][n], 0, 0, 0);
    __syncthreads();
  }
  const int rq = (lane >> 4) * 4;
  float bias[4];
  #pragma unroll
  for (int n = 0; n < 4; n++) bias[n] = b1[(size_t)e * Hdim + hBase + wc * 64 + n * 16 + fr];
  const int rowB = offs[e] + tokBase;
  #pragma unroll
  for (int m = 0; m < 4; m++) {
    #pragma unroll
    for (int j = 0; j < 4; j++) {
      int rl = wr * 64 + m * 16 + rq + j;
      if (tokBase + rl < n_e) {
        size_t rb = (size_t)(rowB + rl) * Hdim + hBase + wc * 64 + fr;
        #pragma unroll
        for (int n = 0; n < 4; n++) {
          float v = fmaxf(acc[m][n][j] + bias[n], 0.f);
          h_buf[rb + n * 16] = f2bf(v * v);
        }
      }
    }
  }
}

// ---------- fc2: y = h @ W2 + b2; out[tok] += gate*y, 128x128 tile ----------
__global__ __launch_bounds__(256)
void fc2_kernel(const u16* __restrict__ h_buf, const u16* __restrict__ W2T,
                const float* __restrict__ b2, const int* __restrict__ counts,
                const int* __restrict__ offs, const int* __restrict__ tok_list,
                const float* __restrict__ gate_list, float* __restrict__ out) {
  const int e = blockIdx.z;
  const int n_e = counts[e];
  const int tokBase = blockIdx.y * 128;
  if (tokBase >= n_e) return;
  const int cBase = blockIdx.x * 128;
  __shared__ u16 As[128 * 32];
  __shared__ u16 Bs[128 * 32];
  __shared__ int toks[128];
  __shared__ float gts[128];
  const int tid = threadIdx.x;
  if (tid < 128) {
    int s = tokBase + tid;
    bool v = s < n_e;
    toks[tid] = v ? tok_list[e * Ntok + s] : 0;
    gts[tid]  = v ? gate_list[e * Ntok + s] : 0.f;
  }
  const int lane = tid & 63, wv = tid >> 6;
  const int wr = wv >> 1, wc = wv & 1;
  const int sRow = lane >> 2, sSlot = lane & 3;
  const int kbOff = (sSlot ^ ((sRow >> 1) & 3)) * 8;
  const int rA0 = wv * 16 + sRow, rA1 = 64 + rA0;
  const int slotB = offs[e] + tokBase;
  const int s0 = min(slotB + rA0, NSLOT - 1);
  const int s1 = min(slotB + rA1, NSLOT - 1);
  const u16* pA0 = h_buf + (size_t)s0 * Hdim + kbOff;
  const u16* pA1 = h_buf + (size_t)s1 * Hdim + kbOff;
  const u16* pB0 = W2T + ((size_t)e * Cdim + cBase + rA0) * Hdim + kbOff;
  const u16* pB1 = W2T + ((size_t)e * Cdim + cBase + rA1) * Hdim + kbOff;
  u16* ldsA0 = As + wv * 512 + lane * 8;
  u16* ldsA1 = As + 2048 + wv * 512 + lane * 8;
  u16* ldsB0 = Bs + wv * 512 + lane * 8;
  u16* ldsB1 = Bs + 2048 + wv * 512 + lane * 8;
  const int fr = lane & 15;
  const int qsw = (((lane >> 4) ^ ((fr >> 1) & 3))) * 8;
  f32x4 acc[4][4] = {};
  for (int k0 = 0; k0 < Hdim; k0 += 32) {
    gld16(pA0 + k0, ldsA0);
    gld16(pA1 + k0, ldsA1);
    gld16(pB0 + k0, ldsB0);
    gld16(pB1 + k0, ldsB1);
    __syncthreads();
    short8 aF[4], bF[4];
    #pragma unroll
    for (int m = 0; m < 4; m++)
      aF[m] = *reinterpret_cast<const short8*>(As + (wr * 64 + m * 16 + fr) * 32 + qsw);
    #pragma unroll
    for (int n = 0; n < 4; n++)
      bF[n] = *reinterpret_cast<const short8*>(Bs + (wc * 64 + n * 16 + fr) * 32 + qsw);
    #pragma unroll
    for (int m = 0; m < 4; m++)
      #pragma unroll
      for (int n = 0; n < 4; n++)
        acc[m][n] = __builtin_amdgcn_mfma_f32_16x16x32_bf16(aF[m], bF[n], acc[m][n], 0, 0, 0);
    __syncthreads();
  }
  const int rq = (lane >> 4) * 4;
  float bias[4];
  #pragma unroll
  for (int n = 0; n < 4; n++) bias[n] = b2[(size_t)e * Cdim + cBase + wc * 64 + n * 16 + fr];
  #pragma unroll
  for (int m = 0; m < 4; m++) {
    #pragma unroll
    for (int j = 0; j < 4; j++) {
      int rl = wr * 64 + m * 16 + rq + j;
      if (tokBase + rl < n_e) {
        int tok = toks[rl];
        float g = gts[rl];
        float* ob = out + (size_t)tok * Cdim + cBase + wc * 64 + fr;
        #pragma unroll
        for (int n = 0; n < 4; n++)
          atomicAdd(ob + n * 16, g * (acc[m][n][j] + bias[n]));
      }
    }
  }
}

extern "C" void kernel_launch(void* const* d_in, const int* in_sizes, int n_in,
                              void* d_out, int out_size, void* d_ws, size_t ws_size,
                              hipStream_t stream) {
  const float* x        = (const float*)d_in[0];
  const float* router_w = (const float*)d_in[1];
  const float* probe_w  = (const float*)d_in[2];
  const float* emb      = (const float*)d_in[3];
  const float* fatigue  = (const float*)d_in[4];
  const float* energy   = (const float*)d_in[5];
  const float* wf1      = (const float*)d_in[6];
  const float* ws1      = (const float*)d_in[7];
  const float* hf1      = (const float*)d_in[8];
  const float* mg1      = (const float*)d_in[9];
  const float* b1       = (const float*)d_in[10];
  const float* wf2      = (const float*)d_in[11];
  const float* ws2      = (const float*)d_in[12];
  const float* hf2      = (const float*)d_in[13];
  const float* mg2      = (const float*)d_in[14];
  const float* b2       = (const float*)d_in[15];
  float* out = (float*)d_out;
  char* ws = (char*)d_ws;

  u16*   x16       = (u16*)(ws + OFF_XB);
  u16*   W1T       = (u16*)(ws + OFF_W1T);
  u16*   W2T       = (u16*)(ws + OFF_W2T);
  u16*   hbuf      = (u16*)(ws + OFF_HBUF);
  int*   tok_list  = (int*)(ws + OFF_TOK);
  float* gate_list = (float*)(ws + OFF_GATE);
  int*   counts    = (int*)(ws + OFF_CNT);
  int*   offs      = (int*)(ws + OFF_OFFS);

  hipMemsetAsync(counts, 0, 64, stream);
  hipMemsetAsync(out, 0, (size_t)Ntok * Cdim * sizeof(float), stream);

  prep_x_kernel<<<1536, 256, 0, stream>>>(x, x16);
  // layer1: in [E][C][H] -> W1T [E][H][C];  layer2: in [E][H][C] -> W2T [E][C][H]
  prep_wt_kernel<<<dim3(Cdim / 64, Hdim / 64, Edim), 256, 0, stream>>>(wf1, ws1, hf1, mg1, W1T, Cdim, Hdim);
  prep_wt_kernel<<<dim3(Hdim / 64, Cdim / 64, Edim), 256, 0, stream>>>(wf2, ws2, hf2, mg2, W2T, Hdim, Cdim);
  router_kernel<<<1024, 256, 0, stream>>>(x, router_w, probe_w, emb, fatigue, energy,
                                          counts, tok_list, gate_list);
  offsets_kernel<<<1, 64, 0, stream>>>(counts, offs);
  fc1_kernel<<<dim3(Hdim / 128, Ntok / 128, Edim), 256, 0, stream>>>(x16, W1T, b1, counts, offs,
                                                                     tok_list, hbuf);
  fc2_kernel<<<dim3(Cdim / 128, Ntok / 128, Edim), 256, 0, stream>>>(hbuf, W2T, b2, counts, offs,
                                                                     tok_list, gate_list, out);
  (void)in_sizes; (void)n_in; (void)out_size; (void)ws_size;
}

// Round 3
// 382.172 us; speedup vs baseline: 1.8187x; 1.0749x over previous
//
#include <hip/hip_runtime.h>

typedef unsigned short u16;
typedef __attribute__((ext_vector_type(8))) short short8;
typedef __attribute__((ext_vector_type(8))) unsigned short ushort8;
typedef __attribute__((ext_vector_type(4))) unsigned short ushort4v;
typedef __attribute__((ext_vector_type(4))) float f32x4;

static constexpr int Cdim = 768;
static constexpr int Hdim = 3072;
static constexpr int Edim = 8;
static constexpr int Ntok = 4096;   // B*T
static constexpr int DRc  = 24;
static constexpr int NSLOT = Ntok * 2;  // 8192
static constexpr int NCHUNK = 8;
static constexpr int CCH = Cdim / NCHUNK;  // 96

// ---- workspace layout (bytes) ----
static constexpr size_t OFF_XB   = 0;                          // x bf16: 6,291,456
static constexpr size_t OFF_W1T  = 6291456;                    // [E][H][C] bf16: 37,748,736
static constexpr size_t OFF_W2T  = 44040192;                   // [E][C][H] bf16: 37,748,736
static constexpr size_t OFF_HBUF = 81788928;                   // 8192*3072*2 = 50,331,648
// xT/part alias the hbuf region (router path finishes before fc1 writes hbuf)
static constexpr size_t OFF_XT   = OFF_HBUF;                   // f32 [C][N]: 12,582,912
static constexpr size_t OFF_PART = OFF_HBUF + 12582912;        // f32 [8][33][N]: 4,325,376
static constexpr size_t OFF_TOK  = 132120576;                  // E*N*4
static constexpr size_t OFF_GATE = 132251648;                  // E*N*4
static constexpr size_t OFF_CNT  = 132382720;                  // 8*4
static constexpr size_t OFF_OFFS = 132382752;                  // 8*4

__device__ __forceinline__ u16 f2bf(float f) {
  unsigned u = __builtin_bit_cast(unsigned, f);
  u += 0x7fffu + ((u >> 16) & 1u);          // round-to-nearest-even
  return (u16)(u >> 16);
}

// async global->LDS, 16B per lane (HW: wave-uniform LDS base + lane*16)
__device__ __forceinline__ void gld16(const u16* g, u16* l) {
  __builtin_amdgcn_global_load_lds((const __attribute__((address_space(1))) unsigned int*)g,
                                   (__attribute__((address_space(3))) unsigned int*)l,
                                   16, 0, 0);
}

// ---------- prep: x -> bf16 [N][C]  AND  x -> f32 transpose [C][N] ----------
__global__ __launch_bounds__(256)
void prep_x2_kernel(const float* __restrict__ x, u16* __restrict__ x16,
                    float* __restrict__ xT) {
  __shared__ float tile[64][65];
  const int c0 = blockIdx.x * 64;
  const int t0 = blockIdx.y * 64;
  const int tid = threadIdx.x;
  const int row = tid >> 4, col = (tid & 15) * 4;
  #pragma unroll
  for (int i = 0; i < 4; i++) {
    int r = row + i * 16;
    size_t idx = (size_t)(t0 + r) * Cdim + c0 + col;
    float4 v = *(const float4*)(x + idx);
    tile[r][col + 0] = v.x; tile[r][col + 1] = v.y;
    tile[r][col + 2] = v.z; tile[r][col + 3] = v.w;
    ushort4v o = { f2bf(v.x), f2bf(v.y), f2bf(v.z), f2bf(v.w) };
    *reinterpret_cast<ushort4v*>(x16 + idx) = o;
  }
  __syncthreads();
  const int c = tid >> 2, tg = (tid & 3) * 16;
  #pragma unroll
  for (int q = 0; q < 4; q++) {
    float4 w;
    w.x = tile[tg + q * 4 + 0][c];
    w.y = tile[tg + q * 4 + 1][c];
    w.z = tile[tg + q * 4 + 2][c];
    w.w = tile[tg + q * 4 + 3][c];
    *reinterpret_cast<float4*>(xT + (size_t)(c0 + c) * Ntok + t0 + tg + q * 4) = w;
  }
}

// ---------- prep: W = wf + mg*ws + hf -> bf16, TRANSPOSED ----------
__global__ __launch_bounds__(256)
void prep_wt_kernel(const float* __restrict__ wf, const float* __restrict__ wsl,
                    const float* __restrict__ hf, const float* __restrict__ mg,
                    u16* __restrict__ outw, const int R, const int Ccol) {
  __shared__ u16 tileT[64][66];
  const int e = blockIdx.z;
  const int r0 = blockIdx.x * 64, c0 = blockIdx.y * 64;
  const float m = mg[e];
  const size_t base = (size_t)e * R * Ccol;
  const int t = threadIdx.x;
  const int cr = t >> 4, cc = (t & 15) * 4;
  #pragma unroll
  for (int i = 0; i < 4; i++) {
    int r = cr + i * 16;
    size_t idx = base + (size_t)(r0 + r) * Ccol + (c0 + cc);
    float4 a = *(const float4*)(wf + idx);
    float4 b = *(const float4*)(wsl + idx);
    float4 h = *(const float4*)(hf + idx);
    tileT[cc + 0][r] = f2bf(fmaf(m, b.x, a.x) + h.x);
    tileT[cc + 1][r] = f2bf(fmaf(m, b.y, a.y) + h.y);
    tileT[cc + 2][r] = f2bf(fmaf(m, b.z, a.z) + h.z);
    tileT[cc + 3][r] = f2bf(fmaf(m, b.w, a.w) + h.w);
  }
  __syncthreads();
  const int oc = t >> 2, ch = (t & 3) * 16;
  ushort8 o0, o1;
  #pragma unroll
  for (int j = 0; j < 8; j++) { o0[j] = tileT[oc][ch + j]; o1[j] = tileT[oc][ch + 8 + j]; }
  size_t oidx = ((size_t)e * Ccol + c0 + oc) * R + r0 + ch;
  *reinterpret_cast<ushort8*>(outw + oidx) = o0;
  *reinterpret_cast<ushort8*>(outw + oidx + 8) = o1;
}

// ---------- router part 1: partial dot-products, one THREAD per token ----------
// part layout: [chunk][o(33)][Ntok], o = 0..7 router, 8..31 probe, 32 sum(x)
__global__ __launch_bounds__(256)
void logits_part_kernel(const float* __restrict__ xT, const float* __restrict__ router_w,
                        const float* __restrict__ probe_w, float* __restrict__ part) {
  const int t = blockIdx.x * 256 + threadIdx.x;
  const int cB = blockIdx.y * CCH;
  float racc[Edim] = {};
  float pacc[DRc] = {};
  float sacc = 0.f;
  for (int ci = 0; ci < CCH; ci++) {
    int c = cB + ci;                       // wave-uniform
    float xv = xT[(size_t)c * Ntok + t];   // coalesced across tokens
    sacc += xv;
    #pragma unroll
    for (int ee = 0; ee < Edim; ee++) racc[ee] = fmaf(xv, router_w[ee * Cdim + c], racc[ee]);
    #pragma unroll
    for (int d = 0; d < DRc; d++) pacc[d] = fmaf(xv, probe_w[d * Cdim + c], pacc[d]);
  }
  float* pb = part + (size_t)blockIdx.y * 33 * Ntok + t;
  #pragma unroll
  for (int ee = 0; ee < Edim; ee++) pb[(size_t)ee * Ntok] = racc[ee];
  #pragma unroll
  for (int d = 0; d < DRc; d++) pb[(size_t)(8 + d) * Ntok] = pacc[d];
  pb[(size_t)32 * Ntok] = sacc;
}

// ---------- router part 2: combine chunks, biases, top-2, softmax, append ----------
__global__ __launch_bounds__(256)
void router_fin_kernel(const float* __restrict__ part, const float* __restrict__ emb,
                       const float* __restrict__ fatigue, const float* __restrict__ energy,
                       int* __restrict__ counts, int* __restrict__ tok_list,
                       float* __restrict__ gate_list) {
  const int t = blockIdx.x * 256 + threadIdx.x;
  float v[33];
  #pragma unroll
  for (int o = 0; o < 33; o++) {
    float s = 0.f;
    #pragma unroll
    for (int ch = 0; ch < NCHUNK; ch++)
      s += part[((size_t)ch * 33 + o) * Ntok + t];   // fixed order -> deterministic
    v[o] = s;
  }
  const float* racc = v;
  const float* pacc = v + 8;
  float proxy = v[32] / 768.f;
  float pn2 = 0.f;
  #pragma unroll
  for (int d = 0; d < DRc; d++) pn2 += pacc[d] * pacc[d];
  float pnorm = sqrtf(pn2);
  float logitv[Edim];
  #pragma unroll
  for (int ee = 0; ee < Edim; ee++) {
    float g2 = 0.f, dote = 0.f;
    #pragma unroll
    for (int d = 0; d < DRc; d++) {
      float ev = emb[ee * DRc + d];
      g2 += ev * ev;
      dote += pacc[d] * ev;
    }
    float gain = sqrtf(g2);
    float align = dote / (fmaxf(pnorm, 1e-12f) * fmaxf(gain, 1e-12f));
    logitv[ee] = racc[ee] + 0.02f * proxy * (1.f + gain) + 0.02f * align
               + 0.1f * energy[ee] - 0.1f * fatigue[ee];
  }
  int e0 = 0; float b0v = logitv[0];
  #pragma unroll
  for (int ee = 1; ee < Edim; ee++) if (logitv[ee] > b0v) { b0v = logitv[ee]; e0 = ee; }
  int e1 = -1; float b1v = -3.4e38f;
  #pragma unroll
  for (int ee = 0; ee < Edim; ee++) if (ee != e0 && logitv[ee] > b1v) { b1v = logitv[ee]; e1 = ee; }
  float texp = expf(b1v - b0v);
  float g0 = 1.f / (1.f + texp);
  float g1 = texp / (1.f + texp);
  int p0 = atomicAdd(&counts[e0], 1);
  tok_list[e0 * Ntok + p0] = t; gate_list[e0 * Ntok + p0] = g0;
  int p1 = atomicAdd(&counts[e1], 1);
  tok_list[e1 * Ntok + p1] = t; gate_list[e1 * Ntok + p1] = g1;
}

__global__ void offsets_kernel(const int* __restrict__ counts, int* __restrict__ offs) {
  if (threadIdx.x == 0) {
    int r = 0;
    for (int e = 0; e < Edim; e++) { offs[e] = r; r += counts[e]; }
  }
}

// ---------- fc1: h = relu(x @ W1 + b1)^2, 128x128 tile, BK=32 ----------
__global__ __launch_bounds__(256)
void fc1_kernel(const u16* __restrict__ x16, const u16* __restrict__ W1T,
                const float* __restrict__ b1, const int* __restrict__ counts,
                const int* __restrict__ offs, const int* __restrict__ tok_list,
                u16* __restrict__ h_buf) {
  const int e = blockIdx.z;
  const int n_e = counts[e];
  const int tokBase = blockIdx.y * 128;
  if (tokBase >= n_e) return;
  const int hBase = blockIdx.x * 128;
  __shared__ u16 As[128 * 32];
  __shared__ u16 Bs[128 * 32];
  __shared__ int toks[128];
  const int tid = threadIdx.x;
  if (tid < 128) {
    int s = tokBase + tid;
    toks[tid] = (s < n_e) ? tok_list[e * Ntok + s] : 0;
  }
  __syncthreads();
  const int lane = tid & 63, wv = tid >> 6;
  const int wr = wv >> 1, wc = wv & 1;
  const int sRow = lane >> 2, sSlot = lane & 3;
  const int kbOff = (sSlot ^ ((sRow >> 1) & 3)) * 8;
  const int rA0 = wv * 16 + sRow, rA1 = 64 + rA0;
  const u16* pA0 = x16 + (size_t)toks[rA0] * Cdim + kbOff;
  const u16* pA1 = x16 + (size_t)toks[rA1] * Cdim + kbOff;
  const u16* pB0 = W1T + ((size_t)e * Hdim + hBase + rA0) * Cdim + kbOff;
  const u16* pB1 = W1T + ((size_t)e * Hdim + hBase + rA1) * Cdim + kbOff;
  u16* ldsA0 = As + wv * 512 + lane * 8;
  u16* ldsA1 = As + 2048 + wv * 512 + lane * 8;
  u16* ldsB0 = Bs + wv * 512 + lane * 8;
  u16* ldsB1 = Bs + 2048 + wv * 512 + lane * 8;
  const int fr = lane & 15;
  const int qsw = (((lane >> 4) ^ ((fr >> 1) & 3))) * 8;
  f32x4 acc[4][4] = {};
  for (int k0 = 0; k0 < Cdim; k0 += 32) {
    gld16(pA0 + k0, ldsA0);
    gld16(pA1 + k0, ldsA1);
    gld16(pB0 + k0, ldsB0);
    gld16(pB1 + k0, ldsB1);
    __syncthreads();
    short8 aF[4], bF[4];
    #pragma unroll
    for (int m = 0; m < 4; m++)
      aF[m] = *reinterpret_cast<const short8*>(As + (wr * 64 + m * 16 + fr) * 32 + qsw);
    #pragma unroll
    for (int n = 0; n < 4; n++)
      bF[n] = *reinterpret_cast<const short8*>(Bs + (wc * 64 + n * 16 + fr) * 32 + qsw);
    #pragma unroll
    for (int m = 0; m < 4; m++)
      #pragma unroll
      for (int n = 0; n < 4; n++)
        acc[m][n] = __builtin_amdgcn_mfma_f32_16x16x32_bf16(aF[m], bF[n], acc[m][n], 0, 0, 0);
    __syncthreads();
  }
  const int rq = (lane >> 4) * 4;
  float bias[4];
  #pragma unroll
  for (int n = 0; n < 4; n++) bias[n] = b1[(size_t)e * Hdim + hBase + wc * 64 + n * 16 + fr];
  const int rowB = offs[e] + tokBase;
  #pragma unroll
  for (int m = 0; m < 4; m++) {
    #pragma unroll
    for (int j = 0; j < 4; j++) {
      int rl = wr * 64 + m * 16 + rq + j;
      if (tokBase + rl < n_e) {
        size_t rb = (size_t)(rowB + rl) * Hdim + hBase + wc * 64 + fr;
        #pragma unroll
        for (int n = 0; n < 4; n++) {
          float v = fmaxf(acc[m][n][j] + bias[n], 0.f);
          h_buf[rb + n * 16] = f2bf(v * v);
        }
      }
    }
  }
}

// ---------- fc2: y = h @ W2 + b2; out[tok] += gate*y, 128x128 tile ----------
__global__ __launch_bounds__(256)
void fc2_kernel(const u16* __restrict__ h_buf, const u16* __restrict__ W2T,
                const float* __restrict__ b2, const int* __restrict__ counts,
                const int* __restrict__ offs, const int* __restrict__ tok_list,
                const float* __restrict__ gate_list, float* __restrict__ out) {
  const int e = blockIdx.z;
  const int n_e = counts[e];
  const int tokBase = blockIdx.y * 128;
  if (tokBase >= n_e) return;
  const int cBase = blockIdx.x * 128;
  __shared__ u16 As[128 * 32];
  __shared__ u16 Bs[128 * 32];
  __shared__ int toks[128];
  __shared__ float gts[128];
  const int tid = threadIdx.x;
  if (tid < 128) {
    int s = tokBase + tid;
    bool v = s < n_e;
    toks[tid] = v ? tok_list[e * Ntok + s] : 0;
    gts[tid]  = v ? gate_list[e * Ntok + s] : 0.f;
  }
  const int lane = tid & 63, wv = tid >> 6;
  const int wr = wv >> 1, wc = wv & 1;
  const int sRow = lane >> 2, sSlot = lane & 3;
  const int kbOff = (sSlot ^ ((sRow >> 1) & 3)) * 8;
  const int rA0 = wv * 16 + sRow, rA1 = 64 + rA0;
  const int slotB = offs[e] + tokBase;
  const int s0 = min(slotB + rA0, NSLOT - 1);
  const int s1 = min(slotB + rA1, NSLOT - 1);
  const u16* pA0 = h_buf + (size_t)s0 * Hdim + kbOff;
  const u16* pA1 = h_buf + (size_t)s1 * Hdim + kbOff;
  const u16* pB0 = W2T + ((size_t)e * Cdim + cBase + rA0) * Hdim + kbOff;
  const u16* pB1 = W2T + ((size_t)e * Cdim + cBase + rA1) * Hdim + kbOff;
  u16* ldsA0 = As + wv * 512 + lane * 8;
  u16* ldsA1 = As + 2048 + wv * 512 + lane * 8;
  u16* ldsB0 = Bs + wv * 512 + lane * 8;
  u16* ldsB1 = Bs + 2048 + wv * 512 + lane * 8;
  const int fr = lane & 15;
  const int qsw = (((lane >> 4) ^ ((fr >> 1) & 3))) * 8;
  f32x4 acc[4][4] = {};
  for (int k0 = 0; k0 < Hdim; k0 += 32) {
    gld16(pA0 + k0, ldsA0);
    gld16(pA1 + k0, ldsA1);
    gld16(pB0 + k0, ldsB0);
    gld16(pB1 + k0, ldsB1);
    __syncthreads();
    short8 aF[4], bF[4];
    #pragma unroll
    for (int m = 0; m < 4; m++)
      aF[m] = *reinterpret_cast<const short8*>(As + (wr * 64 + m * 16 + fr) * 32 + qsw);
    #pragma unroll
    for (int n = 0; n < 4; n++)
      bF[n] = *reinterpret_cast<const short8*>(Bs + (wc * 64 + n * 16 + fr) * 32 + qsw);
    #pragma unroll
    for (int m = 0; m < 4; m++)
      #pragma unroll
      for (int n = 0; n < 4; n++)
        acc[m][n] = __builtin_amdgcn_mfma_f32_16x16x32_bf16(aF[m], bF[n], acc[m][n], 0, 0, 0);
    __syncthreads();
  }
  const int rq = (lane >> 4) * 4;
  float bias[4];
  #pragma unroll
  for (int n = 0; n < 4; n++) bias[n] = b2[(size_t)e * Cdim + cBase + wc * 64 + n * 16 + fr];
  #pragma unroll
  for (int m = 0; m < 4; m++) {
    #pragma unroll
    for (int j = 0; j < 4; j++) {
      int rl = wr * 64 + m * 16 + rq + j;
      if (tokBase + rl < n_e) {
        int tok = toks[rl];
        float g = gts[rl];
        float* ob = out + (size_t)tok * Cdim + cBase + wc * 64 + fr;
        #pragma unroll
        for (int n = 0; n < 4; n++)
          atomicAdd(ob + n * 16, g * (acc[m][n][j] + bias[n]));
      }
    }
  }
}

extern "C" void kernel_launch(void* const* d_in, const int* in_sizes, int n_in,
                              void* d_out, int out_size, void* d_ws, size_t ws_size,
                              hipStream_t stream) {
  const float* x        = (const float*)d_in[0];
  const float* router_w = (const float*)d_in[1];
  const float* probe_w  = (const float*)d_in[2];
  const float* emb      = (const float*)d_in[3];
  const float* fatigue  = (const float*)d_in[4];
  const float* energy   = (const float*)d_in[5];
  const float* wf1      = (const float*)d_in[6];
  const float* ws1      = (const float*)d_in[7];
  const float* hf1      = (const float*)d_in[8];
  const float* mg1      = (const float*)d_in[9];
  const float* b1       = (const float*)d_in[10];
  const float* wf2      = (const float*)d_in[11];
  const float* ws2      = (const float*)d_in[12];
  const float* hf2      = (const float*)d_in[13];
  const float* mg2      = (const float*)d_in[14];
  const float* b2       = (const float*)d_in[15];
  float* out = (float*)d_out;
  char* ws = (char*)d_ws;

  u16*   x16       = (u16*)(ws + OFF_XB);
  u16*   W1T       = (u16*)(ws + OFF_W1T);
  u16*   W2T       = (u16*)(ws + OFF_W2T);
  u16*   hbuf      = (u16*)(ws + OFF_HBUF);
  float* xT        = (float*)(ws + OFF_XT);
  float* part      = (float*)(ws + OFF_PART);
  int*   tok_list  = (int*)(ws + OFF_TOK);
  float* gate_list = (float*)(ws + OFF_GATE);
  int*   counts    = (int*)(ws + OFF_CNT);
  int*   offs      = (int*)(ws + OFF_OFFS);

  hipMemsetAsync(counts, 0, 64, stream);
  hipMemsetAsync(out, 0, (size_t)Ntok * Cdim * sizeof(float), stream);

  prep_x2_kernel<<<dim3(Cdim / 64, Ntok / 64), 256, 0, stream>>>(x, x16, xT);
  logits_part_kernel<<<dim3(Ntok / 256, NCHUNK), 256, 0, stream>>>(xT, router_w, probe_w, part);
  router_fin_kernel<<<Ntok / 256, 256, 0, stream>>>(part, emb, fatigue, energy,
                                                    counts, tok_list, gate_list);
  // layer1: in [E][C][H] -> W1T [E][H][C];  layer2: in [E][H][C] -> W2T [E][C][H]
  prep_wt_kernel<<<dim3(Cdim / 64, Hdim / 64, Edim), 256, 0, stream>>>(wf1, ws1, hf1, mg1, W1T, Cdim, Hdim);
  prep_wt_kernel<<<dim3(Hdim / 64, Cdim / 64, Edim), 256, 0, stream>>>(wf2, ws2, hf2, mg2, W2T, Hdim, Cdim);
  offsets_kernel<<<1, 64, 0, stream>>>(counts, offs);
  fc1_kernel<<<dim3(Hdim / 128, Ntok / 128, Edim), 256, 0, stream>>>(x16, W1T, b1, counts, offs,
                                                                     tok_list, hbuf);
  fc2_kernel<<<dim3(Cdim / 128, Ntok / 128, Edim), 256, 0, stream>>>(hbuf, W2T, b2, counts, offs,
                                                                     tok_list, gate_list, out);
  (void)in_sizes; (void)n_in; (void)out_size; (void)ws_size;
}